// Round 3
// baseline (520.688 us; speedup 1.0000x reference)
//
#include <hip/hip_runtime.h>
#include <hip/hip_bf16.h>

#define B_ 4
#define T_ 8192
#define N_ 64
#define F_ 16
#define O_ 32

typedef _Float16 half8_t __attribute__((ext_vector_type(8)));
typedef _Float16 half4_t __attribute__((ext_vector_type(4)));
typedef float float4_t __attribute__((ext_vector_type(4)));

// ---------------- workspace layout (byte offsets, NON-overlapping) --------
// A1   : 0       size 16384   (4096 f32)   [b][n][f]  zeroed (atomics)
// G    : 16384   size 16384   (4096 f32)   [b][m][f]  zeroed (atomics)
// ZERO : 32768   size 4096    zero page for conv boundary rows
// Ssc  : 36864   size 65536   (16384 f32)  [b][m][n]  S[b,m,n]*diag(adj)[n]
// Wft  : 102400  size 786432  (393216 f16) [b][o][K]  K = k*1024 + m*16 + f
// xh   : 888832  size 67108864 (f16 copy of x, same layout)
#define WS_A1   0
#define WS_G    16384
#define WS_ZERO 32768
#define WS_SSC  36864
#define WS_WFT  102400ull              // 102400 + 786432 = 888832
#define WS_XH   888832ull
#define WS_XH_END (888832ull + 67108864ull)   // = 67,997,696

// ---------------------------------------------------------------------------
// Kernel A: single pass over x (128 MB). Produces:
//   A1[b,n,f]  += W1[t]*x[b,t,n*16+f]                  (atomics)
//   G[b,m,f]   += sum_t W2[f,t]*rhs[b,m,t]             (atomics; rhs LDS-only)
//     where rhs[b,m,t] = sum_f W3[f]*x[b,t,m*16+f]
//   xh = (f16)x                                         (optional)
// grid = B*(T/32) = 1024 blocks of 256. Loads batched 8-deep for latency.
__global__ __launch_bounds__(256) void kA(const float* __restrict__ x,
                                          const float* __restrict__ W1,
                                          const float* __restrict__ W2,
                                          const float* __restrict__ W3,
                                          float* __restrict__ A1,
                                          float* __restrict__ G,
                                          _Float16* __restrict__ xh) {
    __shared__ float ldsr[64][33];   // rhs tile [n][t-local], padded
    __shared__ float w2t[16][32];    // W2 tile  [f][t-local]
    const int b   = blockIdx.x >> 8;
    const int t0  = (blockIdx.x & 255) * 32;
    const int tid = threadIdx.x;
    const int n   = tid >> 2;        // vertex
    const int fq  = tid & 3;         // f-quarter

    for (int i = tid; i < 512; i += 256)
        w2t[i >> 5][i & 31] = W2[(i >> 5) * T_ + t0 + (i & 31)];

    float w3v[4];
#pragma unroll
    for (int j = 0; j < 4; ++j) w3v[j] = W3[fq * 4 + j];

    const float* xbase = x + (size_t)b * T_ * 1024 + tid * 4;
    _Float16* xhb = xh ? (xh + (size_t)b * T_ * 1024 + tid * 4) : nullptr;
    float accA[4] = {0.f, 0.f, 0.f, 0.f};

    for (int g = 0; g < 4; ++g) {
        float4_t xv[8];
#pragma unroll
        for (int r = 0; r < 8; ++r)          // 8 independent loads in flight
            xv[r] = *(const float4_t*)(xbase + (size_t)(t0 + g * 8 + r) * 1024);
#pragma unroll
        for (int r = 0; r < 8; ++r) {
            const int t = t0 + g * 8 + r;
            const float w1 = W1[t];
            float v = xv[r][0] * w3v[0] + xv[r][1] * w3v[1] +
                      xv[r][2] * w3v[2] + xv[r][3] * w3v[3];
            v += __shfl_xor(v, 1);
            v += __shfl_xor(v, 2);
            if (fq == 0) ldsr[n][g * 8 + r] = v;
#pragma unroll
            for (int j = 0; j < 4; ++j) accA[j] += w1 * xv[r][j];
            if (xhb) {
                half4_t h;
                h[0] = (_Float16)xv[r][0]; h[1] = (_Float16)xv[r][1];
                h[2] = (_Float16)xv[r][2]; h[3] = (_Float16)xv[r][3];
                *(half4_t*)(xhb + (size_t)t * 1024) = h;
            }
        }
    }
#pragma unroll
    for (int j = 0; j < 4; ++j)
        atomicAdd(&A1[(b * 64 + n) * 16 + fq * 4 + j], accA[j]);

    __syncthreads();
    // G partials from the LDS rhs tile. wave w handles f-group fg; lane -> m.
    const int m = tid & 63, fg = tid >> 6;
    float gacc[4] = {0.f, 0.f, 0.f, 0.f};
#pragma unroll 8
    for (int tt = 0; tt < 32; ++tt) {
        const float rv = ldsr[m][tt];          // 2-way alias: free
#pragma unroll
        for (int j = 0; j < 4; ++j) gacc[j] += w2t[fg * 4 + j][tt] * rv;
    }
#pragma unroll
    for (int j = 0; j < 4; ++j)
        atomicAdd(&G[(b * 64 + m) * 16 + fg * 4 + j], gacc[j]);
}

// ---------------------------------------------------------------------------
// Kernel C: per-b attention matrix (unchanged; validated round 1).
__global__ __launch_bounds__(256) void kC(const float* __restrict__ A1,
                                          const float* __restrict__ G,
                                          const float* __restrict__ bs,
                                          const float* __restrict__ Vs,
                                          const float* __restrict__ adj,
                                          float* __restrict__ Ssc) {
    const int b = blockIdx.x;
    __shared__ float a1[64][17], g[64][17];
    __shared__ float sig[64][64], s0[64][64];
    const int tid = threadIdx.x;

    for (int i = tid; i < 1024; i += 256) {
        a1[i >> 4][i & 15] = A1[b * 1024 + i];
        g [i >> 4][i & 15] = G [b * 1024 + i];
    }
    __syncthreads();

#pragma unroll
    for (int i = 0; i < 16; ++i) {
        const int e = tid + 256 * i, r = e >> 6, c = e & 63;
        float p = 0.f;
#pragma unroll
        for (int f = 0; f < 16; ++f) p += a1[r][f] * g[c][f];
        p += bs[e];
        sig[r][c] = 1.f / (1.f + __expf(-p));
    }
    __syncthreads();

#pragma unroll
    for (int i = 0; i < 16; ++i) {
        const int e = tid + 256 * i, r = e >> 6, c = e & 63;
        float s = 0.f;
        for (int m = 0; m < 64; ++m) s += Vs[r * 64 + m] * sig[m][c];
        s0[r][c] = s;
    }
    __syncthreads();

    if (tid < 64) {
        const int c = tid;
        float mx = -1e30f;
        for (int r = 0; r < 64; ++r) mx = fmaxf(mx, s0[r][c]);
        float sum = 0.f;
        for (int r = 0; r < 64; ++r) { const float ev = __expf(s0[r][c] - mx); s0[r][c] = ev; sum += ev; }
        const float inv = 1.f / sum;
        const float dg = adj[c * 64 + c];
        for (int r = 0; r < 64; ++r)
            Ssc[b * 4096 + r * 64 + c] = s0[r][c] * inv * dg;
    }
}

// ---------------------------------------------------------------------------
// Kernel D: fold conv weights through attention (unchanged; validated).
__global__ __launch_bounds__(256) void kD(const float* __restrict__ Ssc,
                                          const float* __restrict__ conv_w,
                                          _Float16* __restrict__ Wft) {
    const int b = blockIdx.x >> 5, o = blockIdx.x & 31;
    __shared__ float ssc[4096];
    __shared__ float cw[3072];
    const int tid = threadIdx.x;
    for (int i = tid; i < 4096; i += 256) ssc[i] = Ssc[b * 4096 + i];
    for (int i = tid; i < 3072; i += 256) cw[i] = conv_w[o * 3072 + i];
    __syncthreads();

#pragma unroll
    for (int i = 0; i < 12; ++i) {
        const int e = tid + 256 * i;
        const int k = e >> 10, rem = e & 1023, m = rem >> 4, f = rem & 15;
        float s = 0.f;
#pragma unroll
        for (int n = 0; n < 64; ++n) s += cw[(n * 16 + f) * 3 + k] * ssc[m * 64 + n];
        Wft[(size_t)(b * 32 + o) * 3072 + e] = (_Float16)s;
    }
}

// ---------------------------------------------------------------------------
// Kernel E (fast): out = conv(xh, Wft) via f16 MFMA, no conversions in loop.
// Wave tile 16t x 32o; tap-major loop with zero-page pointer for boundaries.
__global__ __launch_bounds__(256) void kE16(const _Float16* __restrict__ xh,
                                            const _Float16* __restrict__ Wft,
                                            const _Float16* __restrict__ zrow,
                                            float* __restrict__ out) {
    const int b    = blockIdx.x >> 7;
    const int tile = blockIdx.x & 127;
    const int wave = threadIdx.x >> 6;
    const int lane = threadIdx.x & 63;
    const int q = lane >> 4, l = lane & 15;
    const int t0 = tile * 64 + wave * 16;

    const _Float16* wb0 = Wft + (size_t)(b * 32 + l) * 3072;
    const _Float16* wb1 = wb0 + 16 * 3072;
    const _Float16* xb  = xh + (size_t)b * T_ * 1024;

    float4_t acc0 = {0.f, 0.f, 0.f, 0.f};
    float4_t acc1 = {0.f, 0.f, 0.f, 0.f};

#pragma unroll
    for (int kc = 0; kc < 3; ++kc) {
        const int row = t0 + l + kc - 1;
        const _Float16* ap = ((unsigned)row < (unsigned)T_)
                                 ? (xb + (size_t)row * 1024 + q * 8)
                                 : (zrow + q * 8);
        const _Float16* bp0 = wb0 + kc * 1024 + q * 8;
        const _Float16* bp1 = wb1 + kc * 1024 + q * 8;
#pragma unroll 8
        for (int cb = 0; cb < 32; ++cb) {
            half8_t a  = *(const half8_t*)(ap  + cb * 32);
            half8_t b0 = *(const half8_t*)(bp0 + cb * 32);
            half8_t b1 = *(const half8_t*)(bp1 + cb * 32);
            acc0 = __builtin_amdgcn_mfma_f32_16x16x32_f16(a, b0, acc0, 0, 0, 0);
            acc1 = __builtin_amdgcn_mfma_f32_16x16x32_f16(a, b1, acc1, 0, 0, 0);
        }
    }
#pragma unroll
    for (int rg = 0; rg < 4; ++rg) {
        const int t = t0 + q * 4 + rg;
        float* op = out + ((size_t)b * T_ + t) * 32;
        op[l]      = acc0[rg];
        op[16 + l] = acc1[rg];
    }
}

// Kernel E (fallback, ws too small for xh): reads f32 x, converts in-loop.
__global__ __launch_bounds__(256) void kE32(const float* __restrict__ x,
                                            const _Float16* __restrict__ Wft,
                                            const float* __restrict__ zrowf,
                                            float* __restrict__ out) {
    const int b    = blockIdx.x >> 7;
    const int tile = blockIdx.x & 127;
    const int wave = threadIdx.x >> 6;
    const int lane = threadIdx.x & 63;
    const int q = lane >> 4, l = lane & 15;
    const int t0 = tile * 64 + wave * 16;

    const _Float16* wb0 = Wft + (size_t)(b * 32 + l) * 3072;
    const _Float16* wb1 = wb0 + 16 * 3072;
    const float* xb = x + (size_t)b * T_ * 1024;

    float4_t acc0 = {0.f, 0.f, 0.f, 0.f};
    float4_t acc1 = {0.f, 0.f, 0.f, 0.f};

#pragma unroll
    for (int kc = 0; kc < 3; ++kc) {
        const int row = t0 + l + kc - 1;
        const float* ap = ((unsigned)row < (unsigned)T_)
                              ? (xb + (size_t)row * 1024 + q * 8)
                              : (zrowf + q * 8);
        const _Float16* bp0 = wb0 + kc * 1024 + q * 8;
        const _Float16* bp1 = wb1 + kc * 1024 + q * 8;
#pragma unroll 4
        for (int cb = 0; cb < 32; ++cb) {
            float4_t a0 = *(const float4_t*)(ap + cb * 32);
            float4_t a1 = *(const float4_t*)(ap + cb * 32 + 4);
            half8_t a;
            a[0] = (_Float16)a0[0]; a[1] = (_Float16)a0[1];
            a[2] = (_Float16)a0[2]; a[3] = (_Float16)a0[3];
            a[4] = (_Float16)a1[0]; a[5] = (_Float16)a1[1];
            a[6] = (_Float16)a1[2]; a[7] = (_Float16)a1[3];
            half8_t b0 = *(const half8_t*)(bp0 + cb * 32);
            half8_t b1 = *(const half8_t*)(bp1 + cb * 32);
            acc0 = __builtin_amdgcn_mfma_f32_16x16x32_f16(a, b0, acc0, 0, 0, 0);
            acc1 = __builtin_amdgcn_mfma_f32_16x16x32_f16(a, b1, acc1, 0, 0, 0);
        }
    }
#pragma unroll
    for (int rg = 0; rg < 4; ++rg) {
        const int t = t0 + q * 4 + rg;
        float* op = out + ((size_t)b * T_ + t) * 32;
        op[l]      = acc0[rg];
        op[16 + l] = acc1[rg];
    }
}

// ---------------------------------------------------------------------------
extern "C" void kernel_launch(void* const* d_in, const int* in_sizes, int n_in,
                              void* d_out, int out_size, void* d_ws, size_t ws_size,
                              hipStream_t stream) {
    const float* x      = (const float*)d_in[0];
    const float* adj    = (const float*)d_in[1];
    const float* W1     = (const float*)d_in[2];
    const float* W2     = (const float*)d_in[3];
    const float* W3     = (const float*)d_in[4];
    const float* bs     = (const float*)d_in[5];
    const float* Vs     = (const float*)d_in[6];
    const float* conv_w = (const float*)d_in[7];
    float* out = (float*)d_out;

    char* ws = (char*)d_ws;
    float*    A1   = (float*)(ws + WS_A1);
    float*    G    = (float*)(ws + WS_G);
    float*    zpg  = (float*)(ws + WS_ZERO);
    float*    Ssc  = (float*)(ws + WS_SSC);
    _Float16* Wft  = (_Float16*)(ws + WS_WFT);
    _Float16* xhp  = (_Float16*)(ws + WS_XH);

    const bool fast = (ws_size >= WS_XH_END);

    // zero A1, G (atomic targets) and the boundary zero page + padding
    hipMemsetAsync(ws, 0, 36864, stream);

    kA<<<B_ * (T_ / 32), 256, 0, stream>>>(x, W1, W2, W3, A1, G,
                                           fast ? xhp : (_Float16*)nullptr);
    kC<<<B_,             256, 0, stream>>>(A1, G, bs, Vs, adj, Ssc);
    kD<<<B_ * O_,        256, 0, stream>>>(Ssc, conv_w, Wft);
    if (fast)
        kE16<<<B_ * (T_ / 64), 256, 0, stream>>>(xhp, Wft, (const _Float16*)zpg, out);
    else
        kE32<<<B_ * (T_ / 64), 256, 0, stream>>>(x, Wft, zpg, out);
}